// Round 3
// baseline (760.889 us; speedup 1.0000x reference)
//
#include <hip/hip_runtime.h>
#include <cstdint>
#include <cstddef>

typedef float  f32x4 __attribute__((ext_vector_type(4)));
typedef short  s16x8 __attribute__((ext_vector_type(8)));

#define NTOK   49
#define CDIM   192
#define HEADS  6
#define SCALE  0.17677669529663689f   // 1/sqrt(32)

static __device__ __forceinline__ ushort f2bf(float f) {
  union { float f; uint32_t u; } v; v.f = f;
  uint32_t r = (v.u + 0x7FFFu + ((v.u >> 16) & 1u)) >> 16;  // RNE
  return (ushort)r;
}

static __device__ __forceinline__ f32x4 mfma_bf16(s16x8 a, s16x8 b, f32x4 c) {
  return __builtin_amdgcn_mfma_f32_16x16x32_bf16(a, b, c, 0, 0, 0);
}

__global__ void wconv_kernel(const float* __restrict__ qkv_w,
                             const float* __restrict__ proj_w,
                             ushort* __restrict__ wq, ushort* __restrict__ wp) {
  int i = blockIdx.x * 256 + threadIdx.x;
  if (i < 576 * 192) wq[i] = f2bf(qkv_w[i]);
  if (i < 192 * 192) wp[i] = f2bf(proj_w[i]);
}

template <bool WB>
__global__ __launch_bounds__(384)
void wattn_kernel(const float* __restrict__ x,
                  const float* __restrict__ qkv_w, const float* __restrict__ qkv_b,
                  const float* __restrict__ proj_w, const float* __restrict__ proj_b,
                  const float* __restrict__ bias_table,
                  const ushort* __restrict__ wq, const ushort* __restrict__ wp,
                  float* __restrict__ out) {
  // LDS: 25600 + 30720 + 4096 = 60,416 B  (< 64 KiB)
  __shared__ __align__(16) ushort XB[64 * 200];      // x (bf16); later reused as attn_out
  __shared__ __align__(16) ushort SCR[HEADS * 2560]; // per-wave scratch: Q -> K -> V^T -> P
  __shared__ __align__(16) float  BL[1024];          // bias_table (169*6 used)

  const int tid  = threadIdx.x;
  const int lane = tid & 63;
  const int w    = tid >> 6;     // wave id 0..5 == head id
  const int l16  = lane & 15;
  const int lk   = lane >> 4;    // 0..3
  const int win  = blockIdx.x;

  ushort* scr = &SCR[w * 2560];  // 2560 ushorts = 5120 B per wave

  // ---------------- phase 0: stage x -> bf16 LDS (zero pad rows), bias table ----
  const float* xg = x + (size_t)win * (NTOK * CDIM);
#pragma unroll
  for (int it = 0; it < 8; ++it) {
    int v = tid + it * 384;              // 0..3071 covers 64x192 in float4 units
    int row = v / 48, c4 = v % 48;
    float4 f = {0.f, 0.f, 0.f, 0.f};
    if (row < NTOK) f = *(const float4*)(xg + row * CDIM + c4 * 4);
    ushort4 hh = { f2bf(f.x), f2bf(f.y), f2bf(f.z), f2bf(f.w) };
    *(ushort4*)&XB[row * 200 + c4 * 4] = hh;
  }
  for (int v = tid; v < 169 * 6; v += 384) BL[v] = bias_table[v];
  __syncthreads();

  // ---------------- phase 1: QKV GEMM, wave w computes Q/K/V columns of head w --
  // n(sec,nt2) = sec*192 + w*32 + nt2*16 + l16   (sec: 0=q 1=k 2=v, head-dim 32)
  f32x4 acc[3][2][4] = {};
#pragma unroll
  for (int ks = 0; ks < 6; ++ks) {
    const int k0 = ks * 32 + lk * 8;
    s16x8 a[4];
#pragma unroll
    for (int mt = 0; mt < 4; ++mt)
      a[mt] = *(const s16x8*)&XB[(mt * 16 + l16) * 200 + k0];
#pragma unroll
    for (int sec = 0; sec < 3; ++sec) {
#pragma unroll
      for (int nt2 = 0; nt2 < 2; ++nt2) {
        const int n = sec * 192 + w * 32 + nt2 * 16 + l16;
        s16x8 b;
        if constexpr (WB) {
          b = *(const s16x8*)&wq[n * 192 + k0];
        } else {
          const float* p = qkv_w + n * 192 + k0;
          float4 f0 = *(const float4*)p, f1 = *(const float4*)(p + 4);
          b[0]=(short)f2bf(f0.x); b[1]=(short)f2bf(f0.y); b[2]=(short)f2bf(f0.z); b[3]=(short)f2bf(f0.w);
          b[4]=(short)f2bf(f1.x); b[5]=(short)f2bf(f1.y); b[6]=(short)f2bf(f1.z); b[7]=(short)f2bf(f1.w);
        }
#pragma unroll
        for (int mt = 0; mt < 4; ++mt)
          acc[sec][nt2][mt] = mfma_bf16(a[mt], b, acc[sec][nt2][mt]);
      }
    }
  }
  __syncthreads();   // all XB (x) reads complete; XB may be overwritten in phase 2

  // ---------------- phase 2: per-wave accumulator->fragment transposes + attention
  const int h = w;
  s16x8 aq[4], bk[4], bv[2][2];

  // stage Q: acc layout row=mt*16+lk*4+i, col(dim)=nt2*16+l16 -> scr[tok][dim] (stride 40)
#pragma unroll
  for (int nt2 = 0; nt2 < 2; ++nt2) {
    const float qb = qkv_b[0 * 192 + w * 32 + nt2 * 16 + l16];
#pragma unroll
    for (int mt = 0; mt < 4; ++mt)
#pragma unroll
      for (int i = 0; i < 4; ++i)
        scr[(mt * 16 + lk * 4 + i) * 40 + nt2 * 16 + l16] = f2bf((acc[0][nt2][mt][i] + qb) * SCALE);
  }
  asm volatile("" ::: "memory");
#pragma unroll
  for (int t = 0; t < 4; ++t) aq[t] = *(const s16x8*)&scr[(t * 16 + l16) * 40 + lk * 8];
  asm volatile("" ::: "memory");

  // stage K (overwrites Q region)
#pragma unroll
  for (int nt2 = 0; nt2 < 2; ++nt2) {
    const float kb = qkv_b[1 * 192 + w * 32 + nt2 * 16 + l16];
#pragma unroll
    for (int mt = 0; mt < 4; ++mt)
#pragma unroll
      for (int i = 0; i < 4; ++i)
        scr[(mt * 16 + lk * 4 + i) * 40 + nt2 * 16 + l16] = f2bf(acc[1][nt2][mt][i] + kb);
  }
  asm volatile("" ::: "memory");
#pragma unroll
  for (int t = 0; t < 4; ++t) bk[t] = *(const s16x8*)&scr[(t * 16 + l16) * 40 + lk * 8];
  asm volatile("" ::: "memory");

  // stage V^T: scr[dim][tok] (stride 72), dim = nt2*16+l16, tok = mt*16+lk*4+i
#pragma unroll
  for (int nt2 = 0; nt2 < 2; ++nt2) {
    const float vb = qkv_b[2 * 192 + w * 32 + nt2 * 16 + l16];
#pragma unroll
    for (int mt = 0; mt < 4; ++mt)
#pragma unroll
      for (int i = 0; i < 4; ++i)
        scr[(nt2 * 16 + l16) * 72 + mt * 16 + lk * 4 + i] = f2bf(acc[2][nt2][mt][i] + vb);
  }
  asm volatile("" ::: "memory");
#pragma unroll
  for (int nd = 0; nd < 2; ++nd)
#pragma unroll
    for (int kv = 0; kv < 2; ++kv)
      bv[nd][kv] = *(const s16x8*)&scr[(nd * 16 + l16) * 72 + kv * 32 + lk * 8];
  asm volatile("" ::: "memory");

  // QK^T (pure register MFMA)
  f32x4 S[4][4];
#pragma unroll
  for (int mt = 0; mt < 4; ++mt)
#pragma unroll
    for (int nt = 0; nt < 4; ++nt) {
      f32x4 z = {0.f, 0.f, 0.f, 0.f};
      S[mt][nt] = mfma_bf16(aq[mt], bk[nt], z);
    }

  // relative-position bias + key mask + row softmax
  int cd[4], cm[4]; bool cv[4];
#pragma unroll
  for (int nt = 0; nt < 4; ++nt) {
    const int c = nt * 16 + l16;     // key index
    cv[nt] = (c < NTOK);
    cd[nt] = c / 7; cm[nt] = c % 7;
  }
#pragma unroll
  for (int mt = 0; mt < 4; ++mt) {
#pragma unroll
    for (int i = 0; i < 4; ++i) {
      const int r  = mt * 16 + lk * 4 + i;   // query index
      const int rd = r / 7, rm = r % 7;
#pragma unroll
      for (int nt = 0; nt < 4; ++nt) {
        float sv = S[mt][nt][i];
        if (cv[nt]) {
          int ri = (rd - cd[nt] + 6) * 13 + (rm - cm[nt] + 6);
          ri = ri < 0 ? 0 : (ri > 168 ? 168 : ri);
          sv += BL[ri * 6 + h];
        } else sv = -1e30f;
        S[mt][nt][i] = sv;
      }
      // reduce over the 16 lanes (same lk group) sharing this query row
      float m = S[mt][0][i];
#pragma unroll
      for (int nt = 1; nt < 4; ++nt) m = fmaxf(m, S[mt][nt][i]);
      m = fmaxf(m, __shfl_xor(m, 1));
      m = fmaxf(m, __shfl_xor(m, 2));
      m = fmaxf(m, __shfl_xor(m, 4));
      m = fmaxf(m, __shfl_xor(m, 8));
      float sum = 0.f;
#pragma unroll
      for (int nt = 0; nt < 4; ++nt) {
        float p = exp2f((S[mt][nt][i] - m) * 1.4426950408889634f);
        S[mt][nt][i] = p; sum += p;
      }
      sum += __shfl_xor(sum, 1);
      sum += __shfl_xor(sum, 2);
      sum += __shfl_xor(sum, 4);
      sum += __shfl_xor(sum, 8);
      const float rinv = 1.f / sum;
#pragma unroll
      for (int nt = 0; nt < 4; ++nt) S[mt][nt][i] *= rinv;
    }
  }

  // PV: per mt-tile, transpose P through scratch (stride 72), MFMA with V frags
#pragma unroll
  for (int mt = 0; mt < 4; ++mt) {
#pragma unroll
    for (int nt = 0; nt < 4; ++nt)
#pragma unroll
      for (int i = 0; i < 4; ++i)
        scr[(lk * 4 + i) * 72 + nt * 16 + l16] = f2bf(S[mt][nt][i]);
    asm volatile("" ::: "memory");
    s16x8 ap0 = *(const s16x8*)&scr[l16 * 72 + lk * 8];
    s16x8 ap1 = *(const s16x8*)&scr[l16 * 72 + 32 + lk * 8];
    asm volatile("" ::: "memory");
#pragma unroll
    for (int nd = 0; nd < 2; ++nd) {
      f32x4 z = {0.f, 0.f, 0.f, 0.f};
      f32x4 o = mfma_bf16(ap0, bv[nd][0], z);
      o = mfma_bf16(ap1, bv[nd][1], o);
#pragma unroll
      for (int i = 0; i < 4; ++i)
        XB[(mt * 16 + lk * 4 + i) * 200 + h * 32 + nd * 16 + l16] = f2bf(o[i]);
    }
  }
  __syncthreads();   // attn_out fully written to XB

  // ---------------- phase 3: proj GEMM (wave w -> cols [w*32, w*32+32)) --------
  {
    f32x4 pc[4][2] = {};
#pragma unroll
    for (int ks = 0; ks < 6; ++ks) {
      const int k0 = ks * 32 + lk * 8;
      s16x8 a[4];
#pragma unroll
      for (int mt = 0; mt < 4; ++mt)
        a[mt] = *(const s16x8*)&XB[(mt * 16 + l16) * 200 + k0];
#pragma unroll
      for (int nt = 0; nt < 2; ++nt) {
        const int n = w * 32 + nt * 16 + l16;
        s16x8 b;
        if constexpr (WB) {
          b = *(const s16x8*)&wp[n * 192 + k0];
        } else {
          const float* p = proj_w + n * 192 + k0;
          float4 f0 = *(const float4*)p, f1 = *(const float4*)(p + 4);
          b[0]=(short)f2bf(f0.x); b[1]=(short)f2bf(f0.y); b[2]=(short)f2bf(f0.z); b[3]=(short)f2bf(f0.w);
          b[4]=(short)f2bf(f1.x); b[5]=(short)f2bf(f1.y); b[6]=(short)f2bf(f1.z); b[7]=(short)f2bf(f1.w);
        }
#pragma unroll
        for (int mt = 0; mt < 4; ++mt)
          pc[mt][nt] = mfma_bf16(a[mt], b, pc[mt][nt]);
      }
    }
#pragma unroll
    for (int nt = 0; nt < 2; ++nt) {
      const int n = w * 32 + nt * 16 + l16;
      const float pbias = proj_b[n];
#pragma unroll
      for (int mt = 0; mt < 4; ++mt)
#pragma unroll
        for (int i = 0; i < 4; ++i) {
          const int row = mt * 16 + lk * 4 + i;
          if (row < NTOK)
            out[((size_t)win * NTOK + row) * CDIM + n] = pc[mt][nt][i] + pbias;
        }
    }
  }
}

extern "C" void kernel_launch(void* const* d_in, const int* in_sizes, int n_in,
                              void* d_out, int out_size, void* d_ws, size_t ws_size,
                              hipStream_t stream) {
  const float* x          = (const float*)d_in[0];
  const float* qkv_w      = (const float*)d_in[1];
  const float* qkv_b      = (const float*)d_in[2];
  const float* proj_w     = (const float*)d_in[3];
  const float* proj_b     = (const float*)d_in[4];
  const float* bias_table = (const float*)d_in[5];
  float* out = (float*)d_out;

  const int nwin = in_sizes[0] / (NTOK * CDIM);   // 8192

  const size_t WQ_ELEMS = 576 * 192, WP_ELEMS = 192 * 192;
  const bool wb = ws_size >= (WQ_ELEMS + WP_ELEMS) * sizeof(ushort);

  if (wb) {
    ushort* wq = (ushort*)d_ws;
    ushort* wp = wq + WQ_ELEMS;
    wconv_kernel<<<dim3((unsigned)((WQ_ELEMS + 255) / 256)), dim3(256), 0, stream>>>(
        qkv_w, proj_w, wq, wp);
    wattn_kernel<true><<<dim3(nwin), dim3(384), 0, stream>>>(
        x, qkv_w, qkv_b, proj_w, proj_b, bias_table, wq, wp, out);
  } else {
    wattn_kernel<false><<<dim3(nwin), dim3(384), 0, stream>>>(
        x, qkv_w, qkv_b, proj_w, proj_b, bias_table, nullptr, nullptr, out);
  }
}

// Round 4
// 632.058 us; speedup vs baseline: 1.2038x; 1.2038x over previous
//
#include <hip/hip_runtime.h>
#include <cstdint>
#include <cstddef>

typedef float  f32x4 __attribute__((ext_vector_type(4)));
typedef short  s16x8 __attribute__((ext_vector_type(8)));

#define NTOK   49
#define CDIM   192
#define HEADS  6
#define SCALE  0.17677669529663689f   // 1/sqrt(32)
#define LOG2E  1.4426950408889634f

static __device__ __forceinline__ ushort f2bf(float f) {
  union { float f; uint32_t u; } v; v.f = f;
  uint32_t r = (v.u + 0x7FFFu + ((v.u >> 16) & 1u)) >> 16;  // RNE
  return (ushort)r;
}

static __device__ __forceinline__ s16x8 pack8(f32x4 a, f32x4 b) {
  s16x8 r;
  r[0]=(short)f2bf(a[0]); r[1]=(short)f2bf(a[1]); r[2]=(short)f2bf(a[2]); r[3]=(short)f2bf(a[3]);
  r[4]=(short)f2bf(b[0]); r[5]=(short)f2bf(b[1]); r[6]=(short)f2bf(b[2]); r[7]=(short)f2bf(b[3]);
  return r;
}

static __device__ __forceinline__ f32x4 mfma_bf16(s16x8 a, s16x8 b, f32x4 c) {
  return __builtin_amdgcn_mfma_f32_16x16x32_bf16(a, b, c, 0, 0, 0);
}

__global__ void wconv_kernel(const float* __restrict__ qkv_w,
                             const float* __restrict__ proj_w,
                             ushort* __restrict__ wq, ushort* __restrict__ wp) {
  int i = blockIdx.x * 256 + threadIdx.x;
  if (i < 576 * 192) wq[i] = f2bf(qkv_w[i]);
  if (i < 192 * 192) wp[i] = f2bf(proj_w[i]);
}

template <bool WB>
__global__ __launch_bounds__(384, 3)
void wattn_kernel(const float* __restrict__ x,
                  const float* __restrict__ qkv_w, const float* __restrict__ qkv_b,
                  const float* __restrict__ proj_w, const float* __restrict__ proj_b,
                  const float* __restrict__ bias_table,
                  const ushort* __restrict__ wq, const ushort* __restrict__ wp,
                  float* __restrict__ out) {
  // LDS: 25600 + 4096 = 29,696 B  -> LDS allows 5 blocks/CU; VGPR is the cap
  __shared__ __align__(16) ushort XB[64 * 200];      // x (bf16); later reused as attn_out
  __shared__ __align__(16) float  BL[1024];          // bias_table (169*6 used)

  const int tid  = threadIdx.x;
  const int lane = tid & 63;
  const int w    = tid >> 6;     // wave id 0..5 == head id
  const int l16  = lane & 15;
  const int lk   = lane >> 4;    // 0..3
  const int win  = blockIdx.x;
  const int h    = w;

  // ---------------- phase 0: stage x -> bf16 LDS (zero pad rows), bias table ----
  const float* xg = x + (size_t)win * (NTOK * CDIM);
#pragma unroll
  for (int it = 0; it < 8; ++it) {
    int v = tid + it * 384;              // 0..3071 covers 64x192 in float4 units
    int row = v / 48, c4 = v % 48;
    float4 f = {0.f, 0.f, 0.f, 0.f};
    if (row < NTOK) f = *(const float4*)(xg + row * CDIM + c4 * 4);
    ushort4 hh = { f2bf(f.x), f2bf(f.y), f2bf(f.z), f2bf(f.w) };
    *(ushort4*)&XB[row * 200 + c4 * 4] = hh;
  }
  for (int v = tid; v < 169 * 6; v += 384) BL[v] = bias_table[v];
  __syncthreads();

  // ---------------- phase 1: QKV GEMM, wave w computes head w -------------------
  // Q^T, K^T: mfma(Wfrag, Xfrag) -> D[dim][tok]  (col=l16=tok, row=lk*4+i=dim)
  // V       : mfma(Xfrag, Wfrag) -> D[tok][dim]  (col=l16=dim, row=lk*4+i=tok)
  f32x4 qacc[2][4] = {};   // [dim-tile][tok-tile]
  f32x4 kacc[2][4] = {};
  f32x4 vacc[4][2] = {};   // [tok-tile][dim-tile]
#pragma unroll
  for (int ks = 0; ks < 6; ++ks) {
    const int k0 = ks * 32 + lk * 8;
    s16x8 xa[4];
#pragma unroll
    for (int mt = 0; mt < 4; ++mt)
      xa[mt] = *(const s16x8*)&XB[(mt * 16 + l16) * 200 + k0];
#pragma unroll
    for (int nt2 = 0; nt2 < 2; ++nt2) {
      const int nq = w * 32 + nt2 * 16 + l16;
      s16x8 wqf, wkf, wvf;
      if constexpr (WB) {
        wqf = *(const s16x8*)&wq[(0 * 192 + nq) * 192 + k0];
        wkf = *(const s16x8*)&wq[(1 * 192 + nq) * 192 + k0];
        wvf = *(const s16x8*)&wq[(2 * 192 + nq) * 192 + k0];
      } else {
        const float* p;
        p = qkv_w + (0 * 192 + nq) * 192 + k0;
        { float4 f0 = *(const float4*)p, f1 = *(const float4*)(p + 4);
          f32x4 a = {f0.x,f0.y,f0.z,f0.w}, b = {f1.x,f1.y,f1.z,f1.w}; wqf = pack8(a, b); }
        p = qkv_w + (1 * 192 + nq) * 192 + k0;
        { float4 f0 = *(const float4*)p, f1 = *(const float4*)(p + 4);
          f32x4 a = {f0.x,f0.y,f0.z,f0.w}, b = {f1.x,f1.y,f1.z,f1.w}; wkf = pack8(a, b); }
        p = qkv_w + (2 * 192 + nq) * 192 + k0;
        { float4 f0 = *(const float4*)p, f1 = *(const float4*)(p + 4);
          f32x4 a = {f0.x,f0.y,f0.z,f0.w}, b = {f1.x,f1.y,f1.z,f1.w}; wvf = pack8(a, b); }
      }
#pragma unroll
      for (int mt = 0; mt < 4; ++mt) {
        qacc[nt2][mt] = mfma_bf16(wqf, xa[mt], qacc[nt2][mt]);
        kacc[nt2][mt] = mfma_bf16(wkf, xa[mt], kacc[nt2][mt]);
        vacc[mt][nt2] = mfma_bf16(xa[mt], wvf, vacc[mt][nt2]);
      }
    }
  }
  __syncthreads();   // all XB (x) reads done; XB reusable for attn_out

  // ---------------- phase 2: attention, fully in registers ----------------------
  // Pack K as A-frag, Q as B-frag with permuted k-order {lk*4+i, 16+lk*4+i}.
  s16x8 ak[4], bq[4];
  {
    const float4 qb0 = *(const float4*)&qkv_b[0 * 192 + w * 32 +  0 + lk * 4];
    const float4 qb1 = *(const float4*)&qkv_b[0 * 192 + w * 32 + 16 + lk * 4];
    const float4 kb0 = *(const float4*)&qkv_b[1 * 192 + w * 32 +  0 + lk * 4];
    const float4 kb1 = *(const float4*)&qkv_b[1 * 192 + w * 32 + 16 + lk * 4];
#pragma unroll
    for (int t = 0; t < 4; ++t) {
      f32x4 q0 = qacc[0][t], q1 = qacc[1][t], k0v = kacc[0][t], k1v = kacc[1][t];
      q0[0]=(q0[0]+qb0.x)*SCALE; q0[1]=(q0[1]+qb0.y)*SCALE; q0[2]=(q0[2]+qb0.z)*SCALE; q0[3]=(q0[3]+qb0.w)*SCALE;
      q1[0]=(q1[0]+qb1.x)*SCALE; q1[1]=(q1[1]+qb1.y)*SCALE; q1[2]=(q1[2]+qb1.z)*SCALE; q1[3]=(q1[3]+qb1.w)*SCALE;
      k0v[0]+=kb0.x; k0v[1]+=kb0.y; k0v[2]+=kb0.z; k0v[3]+=kb0.w;
      k1v[0]+=kb1.x; k1v[1]+=kb1.y; k1v[2]+=kb1.z; k1v[3]+=kb1.w;
      bq[t] = pack8(q0, q1);
      ak[t] = pack8(k0v, k1v);
    }
  }

  // S^T = K · Q^T : S[kt][qt], col=l16=query, row=lk*4+i=key (within tiles)
  f32x4 S[4][4];
#pragma unroll
  for (int kt = 0; kt < 4; ++kt)
#pragma unroll
    for (int qt = 0; qt < 4; ++qt) {
      f32x4 z = {0.f, 0.f, 0.f, 0.f};
      S[kt][qt] = mfma_bf16(ak[kt], bq[qt], z);
    }

  // bias + mask + softmax (query is lane-local in l16; reduce over lk via shfl 16/32)
  int kdv[4][4], kmv[4][4];
#pragma unroll
  for (int kt = 0; kt < 4; ++kt)
#pragma unroll
    for (int i = 0; i < 4; ++i) {
      const int key = kt * 16 + lk * 4 + i;
      kdv[kt][i] = key / 7; kmv[kt][i] = key % 7;
    }
#pragma unroll
  for (int qt = 0; qt < 4; ++qt) {
    const int q  = qt * 16 + l16;
    const int qd = q / 7, qm = q % 7;
    float mx = -1e30f;
#pragma unroll
    for (int kt = 0; kt < 4; ++kt)
#pragma unroll
      for (int i = 0; i < 4; ++i) {
        const int key = kt * 16 + lk * 4 + i;
        float sv = S[kt][qt][i];
        if (key < NTOK) {
          int ri = (qd - kdv[kt][i] + 6) * 13 + (qm - kmv[kt][i] + 6);
          ri = ri < 0 ? 0 : (ri > 168 ? 168 : ri);
          sv += BL[ri * 6 + h];
        } else sv = -1e30f;
        S[kt][qt][i] = sv;
        mx = fmaxf(mx, sv);
      }
    mx = fmaxf(mx, __shfl_xor(mx, 16));
    mx = fmaxf(mx, __shfl_xor(mx, 32));
    float sum = 0.f;
#pragma unroll
    for (int kt = 0; kt < 4; ++kt)
#pragma unroll
      for (int i = 0; i < 4; ++i) {
        float p = exp2f((S[kt][qt][i] - mx) * LOG2E);
        S[kt][qt][i] = p; sum += p;
      }
    sum += __shfl_xor(sum, 16);
    sum += __shfl_xor(sum, 32);
    const float rinv = 1.f / sum;
#pragma unroll
    for (int kt = 0; kt < 4; ++kt)
#pragma unroll
      for (int i = 0; i < 4; ++i) S[kt][qt][i] *= rinv;
  }

  // PV: A = P (lane l16 = query, permuted-k over keys), B = V (lane l16 = dim,
  // same permuted-k over tokens). O[qt][nd]: col=l16=dim, row=lk*4+i=query.
  s16x8 bv[2][2];
#pragma unroll
  for (int nd = 0; nd < 2; ++nd) {
    const float vb = qkv_b[2 * 192 + w * 32 + nd * 16 + l16];
    f32x4 v0 = vacc[0][nd], v1 = vacc[1][nd], v2 = vacc[2][nd], v3 = vacc[3][nd];
#pragma unroll
    for (int i = 0; i < 4; ++i) { v0[i]+=vb; v1[i]+=vb; v2[i]+=vb; v3[i]+=vb; }
    bv[nd][0] = pack8(v0, v1);
    bv[nd][1] = pack8(v2, v3);
  }
#pragma unroll
  for (int qt = 0; qt < 4; ++qt) {
    s16x8 pa0 = pack8(S[0][qt], S[1][qt]);
    s16x8 pa1 = pack8(S[2][qt], S[3][qt]);
#pragma unroll
    for (int nd = 0; nd < 2; ++nd) {
      f32x4 z = {0.f, 0.f, 0.f, 0.f};
      f32x4 o = mfma_bf16(pa0, bv[nd][0], z);
      o = mfma_bf16(pa1, bv[nd][1], o);
#pragma unroll
      for (int i = 0; i < 4; ++i)
        XB[(qt * 16 + lk * 4 + i) * 200 + h * 32 + nd * 16 + l16] = f2bf(o[i]);
    }
  }
  __syncthreads();   // attn_out fully written to XB

  // ---------------- phase 3: proj GEMM (wave w -> cols [w*32, w*32+32)) --------
  {
    f32x4 pc[4][2] = {};
#pragma unroll
    for (int ks = 0; ks < 6; ++ks) {
      const int k0 = ks * 32 + lk * 8;
      s16x8 a[4];
#pragma unroll
      for (int mt = 0; mt < 4; ++mt)
        a[mt] = *(const s16x8*)&XB[(mt * 16 + l16) * 200 + k0];
#pragma unroll
      for (int nt = 0; nt < 2; ++nt) {
        const int n = w * 32 + nt * 16 + l16;
        s16x8 b;
        if constexpr (WB) {
          b = *(const s16x8*)&wp[n * 192 + k0];
        } else {
          const float* p = proj_w + n * 192 + k0;
          float4 f0 = *(const float4*)p, f1 = *(const float4*)(p + 4);
          f32x4 fa = {f0.x,f0.y,f0.z,f0.w}, fb = {f1.x,f1.y,f1.z,f1.w};
          b = pack8(fa, fb);
        }
#pragma unroll
        for (int mt = 0; mt < 4; ++mt)
          pc[mt][nt] = mfma_bf16(a[mt], b, pc[mt][nt]);
      }
    }
#pragma unroll
    for (int nt = 0; nt < 2; ++nt) {
      const int n = w * 32 + nt * 16 + l16;
      const float pbias = proj_b[n];
#pragma unroll
      for (int mt = 0; mt < 4; ++mt)
#pragma unroll
        for (int i = 0; i < 4; ++i) {
          const int row = mt * 16 + lk * 4 + i;
          if (row < NTOK)
            out[((size_t)win * NTOK + row) * CDIM + n] = pc[mt][nt][i] + pbias;
        }
    }
  }
}

extern "C" void kernel_launch(void* const* d_in, const int* in_sizes, int n_in,
                              void* d_out, int out_size, void* d_ws, size_t ws_size,
                              hipStream_t stream) {
  const float* x          = (const float*)d_in[0];
  const float* qkv_w      = (const float*)d_in[1];
  const float* qkv_b      = (const float*)d_in[2];
  const float* proj_w     = (const float*)d_in[3];
  const float* proj_b     = (const float*)d_in[4];
  const float* bias_table = (const float*)d_in[5];
  float* out = (float*)d_out;

  const int nwin = in_sizes[0] / (NTOK * CDIM);   // 8192

  const size_t WQ_ELEMS = 576 * 192, WP_ELEMS = 192 * 192;
  const bool wb = ws_size >= (WQ_ELEMS + WP_ELEMS) * sizeof(ushort);

  if (wb) {
    ushort* wq = (ushort*)d_ws;
    ushort* wp = wq + WQ_ELEMS;
    wconv_kernel<<<dim3((unsigned)((WQ_ELEMS + 255) / 256)), dim3(256), 0, stream>>>(
        qkv_w, proj_w, wq, wp);
    wattn_kernel<true><<<dim3(nwin), dim3(384), 0, stream>>>(
        x, qkv_w, qkv_b, proj_w, proj_b, bias_table, wq, wp, out);
  } else {
    wattn_kernel<false><<<dim3(nwin), dim3(384), 0, stream>>>(
        x, qkv_w, qkv_b, proj_w, proj_b, bias_table, nullptr, nullptr, out);
  }
}

// Round 5
// 598.605 us; speedup vs baseline: 1.2711x; 1.0559x over previous
//
#include <hip/hip_runtime.h>
#include <hip/hip_bf16.h>
#include <cstdint>
#include <cstddef>

typedef float  f32x4 __attribute__((ext_vector_type(4)));
typedef short  s16x8 __attribute__((ext_vector_type(8)));

#define NTOK   49
#define CDIM   192
#define HEADS  6
#define SCALE  0.17677669529663689f   // 1/sqrt(32)
#define LOG2E  1.4426950408889634f

// d_ws layout: [biasT: 6*64*64 f32 = 98304 B][wq_s: 576*192 u16 = 221184 B][wp_s: 192*192 u16 = 73728 B]
#define WS_BIAS_BYTES  98304
#define WS_WQ_BYTES    221184
#define WS_TOTAL_BYTES (WS_BIAS_BYTES + WS_WQ_BYTES + 73728)

static __device__ __forceinline__ ushort f2bf(float f) {
  __hip_bfloat16 h = __float2bfloat16(f);   // RNE, HW cvt
  union { __hip_bfloat16 h; ushort u; } c; c.h = h;
  return c.u;
}

static __device__ __forceinline__ s16x8 pack8(f32x4 a, f32x4 b) {
  union { s16x8 v; __hip_bfloat162 h[4]; } u;
  u.h[0] = __float22bfloat162_rn(make_float2(a[0], a[1]));
  u.h[1] = __float22bfloat162_rn(make_float2(a[2], a[3]));
  u.h[2] = __float22bfloat162_rn(make_float2(b[0], b[1]));
  u.h[3] = __float22bfloat162_rn(make_float2(b[2], b[3]));
  return u.v;
}

static __device__ __forceinline__ f32x4 mfma_bf16(s16x8 a, s16x8 b, f32x4 c) {
  return __builtin_amdgcn_mfma_f32_16x16x32_bf16(a, b, c, 0, 0, 0);
}

// fragment-major swizzle: element (n,k) -> ((n>>4)*6 + (k>>5))*512 + ((k>>3)&3)*128 + (n&15)*8 + (k&7)
__global__ void wconv_kernel(const float* __restrict__ qkv_w,
                             const float* __restrict__ proj_w,
                             const float* __restrict__ bias_table,
                             ushort* __restrict__ wqs, ushort* __restrict__ wps,
                             float* __restrict__ biasT) {
  int i = blockIdx.x * 256 + threadIdx.x;
  if (i < 576 * 192) {
    int n = i / 192, k = i % 192;
    int dst = ((n >> 4) * 6 + (k >> 5)) * 512 + ((k >> 3) & 3) * 128 + (n & 15) * 8 + (k & 7);
    wqs[dst] = f2bf(qkv_w[i]);
  }
  if (i < 192 * 192) {
    int n = i / 192, k = i % 192;
    int dst = ((n >> 4) * 6 + (k >> 5)) * 512 + ((k >> 3) & 3) * 128 + (n & 15) * 8 + (k & 7);
    wps[dst] = f2bf(proj_w[i]);
  }
  if (i < HEADS * 64 * 64) {
    int h = i >> 12, rem = i & 4095, key = rem >> 6, q = rem & 63;
    float v;
    if (key >= NTOK)      v = -1e30f;            // mask baked in
    else if (q >= NTOK)   v = 0.f;               // row unused; keep finite
    else {
      int qd = q / 7, qm = q % 7, kd = key / 7, km = key % 7;
      int ri = (qd - kd + 6) * 13 + (qm - km + 6);
      v = bias_table[ri * 6 + h];
    }
    biasT[i] = v;
  }
}

template <bool WB>
__global__ __launch_bounds__(384, 3)
void wattn_kernel(const float* __restrict__ x,
                  const float* __restrict__ qkv_w, const float* __restrict__ qkv_b,
                  const float* __restrict__ proj_w, const float* __restrict__ proj_b,
                  const float* __restrict__ bias_table,
                  const ushort* __restrict__ wqs, const ushort* __restrict__ wps,
                  const float* __restrict__ biasT,
                  float* __restrict__ out) {
  __shared__ __align__(16) ushort XB[64 * 200];      // x (bf16); later reused as attn_out
  __shared__ __align__(16) float  BL[1024];          // bias_table (fallback path only)

  const int tid  = threadIdx.x;
  const int lane = tid & 63;
  const int w    = tid >> 6;     // wave id 0..5 == head id
  const int l16  = lane & 15;
  const int lk   = lane >> 4;    // 0..3
  const int win  = blockIdx.x;
  const int h    = w;

  // ---------------- phase 0: stage x -> bf16 LDS (zero pad rows) ----------------
  const float* xg = x + (size_t)win * (NTOK * CDIM);
#pragma unroll
  for (int it = 0; it < 8; ++it) {
    int v = tid + it * 384;              // 0..3071 covers 64x192 in float4 units
    int row = v / 48, c4 = v % 48;
    float4 f = {0.f, 0.f, 0.f, 0.f};
    if (row < NTOK) f = *(const float4*)(xg + row * CDIM + c4 * 4);
    union { ushort4 u; __hip_bfloat162 h[2]; } cc;
    cc.h[0] = __float22bfloat162_rn(make_float2(f.x, f.y));
    cc.h[1] = __float22bfloat162_rn(make_float2(f.z, f.w));
    *(ushort4*)&XB[row * 200 + c4 * 4] = cc.u;
  }
  if constexpr (!WB) {
    for (int v = tid; v < 169 * 6; v += 384) BL[v] = bias_table[v];
  }
  __syncthreads();

  // ---------------- phase 1: QKV GEMM, wave w computes head w -------------------
  // Q^T, K^T: mfma(Wfrag, Xfrag) -> D[dim][tok]; V: mfma(Xfrag, Wfrag) -> D[tok][dim]
  f32x4 qacc[2][4] = {};   // [dim-tile][tok-tile]
  f32x4 kacc[2][4] = {};
  f32x4 vacc[4][2] = {};   // [tok-tile][dim-tile]
#pragma unroll
  for (int ks = 0; ks < 6; ++ks) {
    const int k0 = ks * 32 + lk * 8;
    s16x8 xa[4];
#pragma unroll
    for (int mt = 0; mt < 4; ++mt)
      xa[mt] = *(const s16x8*)&XB[(mt * 16 + l16) * 200 + k0];
#pragma unroll
    for (int nt2 = 0; nt2 < 2; ++nt2) {
      s16x8 wqf, wkf, wvf;
      if constexpr (WB) {
        // fragment-major: fully-coalesced 1KB/wave loads
        const int lo = lk * 128 + l16 * 8;
        wqf = *(const s16x8*)&wqs[(((0 * 12 + w * 2 + nt2) * 6 + ks) << 9) + lo];
        wkf = *(const s16x8*)&wqs[(((1 * 12 + w * 2 + nt2) * 6 + ks) << 9) + lo];
        wvf = *(const s16x8*)&wqs[(((2 * 12 + w * 2 + nt2) * 6 + ks) << 9) + lo];
      } else {
        const int nq = w * 32 + nt2 * 16 + l16;
        const float* p;
        p = qkv_w + (0 * 192 + nq) * 192 + k0;
        { float4 f0 = *(const float4*)p, f1 = *(const float4*)(p + 4);
          f32x4 a = {f0.x,f0.y,f0.z,f0.w}, b = {f1.x,f1.y,f1.z,f1.w}; wqf = pack8(a, b); }
        p = qkv_w + (1 * 192 + nq) * 192 + k0;
        { float4 f0 = *(const float4*)p, f1 = *(const float4*)(p + 4);
          f32x4 a = {f0.x,f0.y,f0.z,f0.w}, b = {f1.x,f1.y,f1.z,f1.w}; wkf = pack8(a, b); }
        p = qkv_w + (2 * 192 + nq) * 192 + k0;
        { float4 f0 = *(const float4*)p, f1 = *(const float4*)(p + 4);
          f32x4 a = {f0.x,f0.y,f0.z,f0.w}, b = {f1.x,f1.y,f1.z,f1.w}; wvf = pack8(a, b); }
      }
#pragma unroll
      for (int mt = 0; mt < 4; ++mt) {
        qacc[nt2][mt] = mfma_bf16(wqf, xa[mt], qacc[nt2][mt]);
        kacc[nt2][mt] = mfma_bf16(wkf, xa[mt], kacc[nt2][mt]);
        vacc[mt][nt2] = mfma_bf16(xa[mt], wvf, vacc[mt][nt2]);
      }
    }
  }
  __syncthreads();   // all XB (x) reads done; XB reusable for attn_out

  // ---------------- phase 2: attention, fully in registers ----------------------
  s16x8 ak[4], bq[4];
  {
    const float4 qb0 = *(const float4*)&qkv_b[0 * 192 + w * 32 +  0 + lk * 4];
    const float4 qb1 = *(const float4*)&qkv_b[0 * 192 + w * 32 + 16 + lk * 4];
    const float4 kb0 = *(const float4*)&qkv_b[1 * 192 + w * 32 +  0 + lk * 4];
    const float4 kb1 = *(const float4*)&qkv_b[1 * 192 + w * 32 + 16 + lk * 4];
#pragma unroll
    for (int t = 0; t < 4; ++t) {
      f32x4 q0 = qacc[0][t], q1 = qacc[1][t], k0v = kacc[0][t], k1v = kacc[1][t];
      q0[0]=(q0[0]+qb0.x)*SCALE; q0[1]=(q0[1]+qb0.y)*SCALE; q0[2]=(q0[2]+qb0.z)*SCALE; q0[3]=(q0[3]+qb0.w)*SCALE;
      q1[0]=(q1[0]+qb1.x)*SCALE; q1[1]=(q1[1]+qb1.y)*SCALE; q1[2]=(q1[2]+qb1.z)*SCALE; q1[3]=(q1[3]+qb1.w)*SCALE;
      k0v[0]+=kb0.x; k0v[1]+=kb0.y; k0v[2]+=kb0.z; k0v[3]+=kb0.w;
      k1v[0]+=kb1.x; k1v[1]+=kb1.y; k1v[2]+=kb1.z; k1v[3]+=kb1.w;
      bq[t] = pack8(q0, q1);
      ak[t] = pack8(k0v, k1v);
    }
  }

  // S^T = K · Q^T : S[kt][qt], col=l16=query, row=lk*4+i=key (within tiles)
  f32x4 S[4][4];
#pragma unroll
  for (int kt = 0; kt < 4; ++kt)
#pragma unroll
    for (int qt = 0; qt < 4; ++qt) {
      f32x4 z = {0.f, 0.f, 0.f, 0.f};
      S[kt][qt] = mfma_bf16(ak[kt], bq[qt], z);
    }

  // bias (+baked mask) + softmax; query lane-local in l16, reduce over lk via shfl
  if constexpr (WB) {
    const float* bb = biasT + (h * 64 + lk * 4) * 64 + l16;
#pragma unroll
    for (int qt = 0; qt < 4; ++qt) {
      float mx = -1e30f;
#pragma unroll
      for (int kt = 0; kt < 4; ++kt)
#pragma unroll
        for (int i = 0; i < 4; ++i) {
          float sv = S[kt][qt][i] + bb[(kt * 16 + i) * 64 + qt * 16];
          S[kt][qt][i] = sv;
          mx = fmaxf(mx, sv);
        }
      mx = fmaxf(mx, __shfl_xor(mx, 16));
      mx = fmaxf(mx, __shfl_xor(mx, 32));
      float sum = 0.f;
#pragma unroll
      for (int kt = 0; kt < 4; ++kt)
#pragma unroll
        for (int i = 0; i < 4; ++i) {
          float p = exp2f((S[kt][qt][i] - mx) * LOG2E);
          S[kt][qt][i] = p; sum += p;
        }
      sum += __shfl_xor(sum, 16);
      sum += __shfl_xor(sum, 32);
      const float rinv = 1.f / sum;
#pragma unroll
      for (int kt = 0; kt < 4; ++kt)
#pragma unroll
        for (int i = 0; i < 4; ++i) S[kt][qt][i] *= rinv;
    }
  } else {
    int kdv[4][4], kmv[4][4];
#pragma unroll
    for (int kt = 0; kt < 4; ++kt)
#pragma unroll
      for (int i = 0; i < 4; ++i) {
        const int key = kt * 16 + lk * 4 + i;
        kdv[kt][i] = key / 7; kmv[kt][i] = key % 7;
      }
#pragma unroll
    for (int qt = 0; qt < 4; ++qt) {
      const int q  = qt * 16 + l16;
      const int qd = q / 7, qm = q % 7;
      float mx = -1e30f;
#pragma unroll
      for (int kt = 0; kt < 4; ++kt)
#pragma unroll
        for (int i = 0; i < 4; ++i) {
          const int key = kt * 16 + lk * 4 + i;
          float sv = S[kt][qt][i];
          if (key < NTOK) {
            int ri = (qd - kdv[kt][i] + 6) * 13 + (qm - kmv[kt][i] + 6);
            ri = ri < 0 ? 0 : (ri > 168 ? 168 : ri);
            sv += BL[ri * 6 + h];
          } else sv = -1e30f;
          S[kt][qt][i] = sv;
          mx = fmaxf(mx, sv);
        }
      mx = fmaxf(mx, __shfl_xor(mx, 16));
      mx = fmaxf(mx, __shfl_xor(mx, 32));
      float sum = 0.f;
#pragma unroll
      for (int kt = 0; kt < 4; ++kt)
#pragma unroll
        for (int i = 0; i < 4; ++i) {
          float p = exp2f((S[kt][qt][i] - mx) * LOG2E);
          S[kt][qt][i] = p; sum += p;
        }
      sum += __shfl_xor(sum, 16);
      sum += __shfl_xor(sum, 32);
      const float rinv = 1.f / sum;
#pragma unroll
      for (int kt = 0; kt < 4; ++kt)
#pragma unroll
        for (int i = 0; i < 4; ++i) S[kt][qt][i] *= rinv;
    }
  }

  // PV: A = P (permuted-k over keys), B = V (same permuted-k over tokens)
  s16x8 bv[2][2];
#pragma unroll
  for (int nd = 0; nd < 2; ++nd) {
    const float vb = qkv_b[2 * 192 + w * 32 + nd * 16 + l16];
    f32x4 v0 = vacc[0][nd], v1 = vacc[1][nd], v2 = vacc[2][nd], v3 = vacc[3][nd];
#pragma unroll
    for (int i = 0; i < 4; ++i) { v0[i]+=vb; v1[i]+=vb; v2[i]+=vb; v3[i]+=vb; }
    bv[nd][0] = pack8(v0, v1);
    bv[nd][1] = pack8(v2, v3);
  }
#pragma unroll
  for (int qt = 0; qt < 4; ++qt) {
    s16x8 pa0 = pack8(S[0][qt], S[1][qt]);
    s16x8 pa1 = pack8(S[2][qt], S[3][qt]);
#pragma unroll
    for (int nd = 0; nd < 2; ++nd) {
      f32x4 z = {0.f, 0.f, 0.f, 0.f};
      f32x4 o = mfma_bf16(pa0, bv[nd][0], z);
      o = mfma_bf16(pa1, bv[nd][1], o);
#pragma unroll
      for (int i = 0; i < 4; ++i)
        XB[(qt * 16 + lk * 4 + i) * 200 + h * 32 + nd * 16 + l16] = f2bf(o[i]);
    }
  }
  __syncthreads();   // attn_out fully written to XB

  // ---------------- phase 3: proj GEMM (wave w -> cols [w*32, w*32+32)) --------
  {
    f32x4 pc[4][2] = {};
#pragma unroll
    for (int ks = 0; ks < 6; ++ks) {
      const int k0 = ks * 32 + lk * 8;
      s16x8 a[4];
#pragma unroll
      for (int mt = 0; mt < 4; ++mt)
        a[mt] = *(const s16x8*)&XB[(mt * 16 + l16) * 200 + k0];
#pragma unroll
      for (int nt = 0; nt < 2; ++nt) {
        s16x8 b;
        if constexpr (WB) {
          b = *(const s16x8*)&wps[(((w * 2 + nt) * 6 + ks) << 9) + lk * 128 + l16 * 8];
        } else {
          const int n = w * 32 + nt * 16 + l16;
          const float* p = proj_w + n * 192 + k0;
          float4 f0 = *(const float4*)p, f1 = *(const float4*)(p + 4);
          f32x4 fa = {f0.x,f0.y,f0.z,f0.w}, fb = {f1.x,f1.y,f1.z,f1.w};
          b = pack8(fa, fb);
        }
#pragma unroll
        for (int mt = 0; mt < 4; ++mt)
          pc[mt][nt] = mfma_bf16(a[mt], b, pc[mt][nt]);
      }
    }
#pragma unroll
    for (int nt = 0; nt < 2; ++nt) {
      const int n = w * 32 + nt * 16 + l16;
      const float pbias = proj_b[n];
#pragma unroll
      for (int mt = 0; mt < 4; ++mt)
#pragma unroll
        for (int i = 0; i < 4; ++i) {
          const int row = mt * 16 + lk * 4 + i;
          if (row < NTOK)
            out[((size_t)win * NTOK + row) * CDIM + n] = pc[mt][nt][i] + pbias;
        }
    }
  }
}

extern "C" void kernel_launch(void* const* d_in, const int* in_sizes, int n_in,
                              void* d_out, int out_size, void* d_ws, size_t ws_size,
                              hipStream_t stream) {
  const float* x          = (const float*)d_in[0];
  const float* qkv_w      = (const float*)d_in[1];
  const float* qkv_b      = (const float*)d_in[2];
  const float* proj_w     = (const float*)d_in[3];
  const float* proj_b     = (const float*)d_in[4];
  const float* bias_table = (const float*)d_in[5];
  float* out = (float*)d_out;

  const int nwin = in_sizes[0] / (NTOK * CDIM);   // 8192

  if (ws_size >= WS_TOTAL_BYTES) {
    float*  biasT = (float*)d_ws;
    ushort* wqs   = (ushort*)((char*)d_ws + WS_BIAS_BYTES);
    ushort* wps   = (ushort*)((char*)d_ws + WS_BIAS_BYTES + WS_WQ_BYTES);
    wconv_kernel<<<dim3(432), dim3(256), 0, stream>>>(qkv_w, proj_w, bias_table, wqs, wps, biasT);
    wattn_kernel<true><<<dim3(nwin), dim3(384), 0, stream>>>(
        x, qkv_w, qkv_b, proj_w, proj_b, bias_table, wqs, wps, biasT, out);
  } else {
    wattn_kernel<false><<<dim3(nwin), dim3(384), 0, stream>>>(
        x, qkv_w, qkv_b, proj_w, proj_b, bias_table, nullptr, nullptr, nullptr, out);
  }
}